// Round 1
// baseline (230.708 us; speedup 1.0000x reference)
//
#include <hip/hip_runtime.h>
#include <hip/hip_bf16.h>
#include <cstdint>

typedef __bf16 bf16x8 __attribute__((ext_vector_type(8)));
typedef float f32x4 __attribute__((ext_vector_type(4)));

// Problem constants
#define E_DIM 256
#define H_DIM 512
// Ash/Bsh row stride: 32 bf16 + 8 pad = 40 elems = 80B (16B aligned rows, 2-way bank alias only)
#define AB_STRIDE 40

// ---------------- kernel 1: l2-normalize rows of track/det ----------------
// 2048 rows of 256 f32; one wave per row. grid 512 x 256.
__global__ void norm_kernel(const float* __restrict__ track,
                            const float* __restrict__ det,
                            float* __restrict__ tn, float* __restrict__ dn) {
    int row  = blockIdx.x * 4 + (threadIdx.x >> 6);
    int lane = threadIdx.x & 63;
    const float* src;
    float* dst;
    if (row < 1024) { src = track + (size_t)row * E_DIM; dst = tn + (size_t)row * E_DIM; }
    else            { src = det + (size_t)(row - 1024) * E_DIM; dst = dn + (size_t)(row - 1024) * E_DIM; }
    float4 v = ((const float4*)src)[lane];
    float s = v.x*v.x + v.y*v.y + v.z*v.z + v.w*v.w;
#pragma unroll
    for (int off = 32; off > 0; off >>= 1) s += __shfl_xor(s, off);
    float scale = 1.0f / fmaxf(sqrtf(s), 1e-12f);
    float4 o; o.x = v.x*scale; o.y = v.y*scale; o.z = v.z*scale; o.w = v.w*scale;
    ((float4*)dst)[lane] = o;
}

// ---------------- kernel 2: W1c -> bf16, chunk-major [c][h][kk] ----------------
// W1cc[c*16384 + h*32 + kk] = bf16(W1[(512 + c*32 + kk)*512 + h]); 131072 elems, grid 512 x 256.
__global__ void w1c_kernel(const float* __restrict__ W1, __bf16* __restrict__ W1cc) {
    int t  = blockIdx.x * 256 + threadIdx.x;
    int h  = t & 511;
    int kk = (t >> 9) & 31;
    int c  = t >> 14;
    float v = W1[(size_t)(512 + c * 32 + kk) * H_DIM + h];
    W1cc[(size_t)c * 16384 + (size_t)h * 32 + kk] = (__bf16)v;
}

// ---------------- kernel 3: P = tn@W1a + b1 ; Q = dn@W1b (f32) ----------------
// 256 blocks x 512 threads; block = 8 rows x 512 h. blocks <128 -> P, else Q.
__global__ void pq_kernel(const float* __restrict__ tn, const float* __restrict__ dn,
                          const float* __restrict__ W1, const float* __restrict__ b1,
                          float* __restrict__ P, float* __restrict__ Q) {
    __shared__ float xs[8 * E_DIM];
    int blk = blockIdx.x;
    bool isP = blk < 128;
    int r0 = (isP ? blk : blk - 128) * 8;
    const float* src = isP ? tn : dn;
    int t = threadIdx.x;
    ((float4*)xs)[t] = ((const float4*)(src + (size_t)r0 * E_DIM))[t];
    __syncthreads();

    int h = t;  // 0..511
    float acc[8];
    float bias = isP ? b1[h] : 0.0f;
#pragma unroll
    for (int r = 0; r < 8; ++r) acc[r] = bias;
    const float* w = W1 + (isP ? 0 : (size_t)E_DIM * H_DIM) + h;
    const float4* xs4 = (const float4*)xs;  // [8][64]
    for (int e4 = 0; e4 < 64; ++e4) {
        int e = e4 * 4;
        float w0 = w[(size_t)(e + 0) * H_DIM];
        float w1v = w[(size_t)(e + 1) * H_DIM];
        float w2v = w[(size_t)(e + 2) * H_DIM];
        float w3v = w[(size_t)(e + 3) * H_DIM];
#pragma unroll
        for (int r = 0; r < 8; ++r) {
            float4 xv = xs4[r * 64 + e4];
            acc[r] += xv.x * w0 + xv.y * w1v + xv.z * w2v + xv.w * w3v;
        }
    }
    float* dst = (isP ? P : Q) + (size_t)r0 * H_DIM + h;
#pragma unroll
    for (int r = 0; r < 8; ++r) dst[(size_t)r * H_DIM] = acc[r];
}

// ---------------- kernel 4: fused pairwise GEMM + LN + SiLU + W2 dot ----------------
// grid 2048 (b, nt, mt) x 512 threads (8 waves).
// Block tile: 64 pairs (8 n x 8 m) x 512 H; K = 256 in 8 chunks of 32.
// Wave w handles all 64 pairs x H range [w*64, w*64+64): 4x4 tiles of 16x16x32 MFMA.
__global__ __launch_bounds__(512, 2)
void main_kernel(const float* __restrict__ tn, const float* __restrict__ dn,
                 const __bf16* __restrict__ W1cc,
                 const float* __restrict__ P, const float* __restrict__ Q,
                 const float* __restrict__ gamma, const float* __restrict__ beta,
                 const float* __restrict__ W2, const float* __restrict__ b2,
                 float* __restrict__ out) {
    __shared__ float tsl[8 * E_DIM];                 // 8 KB
    __shared__ float dsl[8 * E_DIM];                 // 8 KB
    __shared__ __bf16 Ash[64][AB_STRIDE];            // 5 KB
    __shared__ __bf16 Bsh[H_DIM][AB_STRIDE];         // 40 KB
    __shared__ float LNr1[64][8];                    // 2 KB
    __shared__ float LNr2[64][8];                    // 2 KB
    __shared__ float MuS[64];
    __shared__ float RsS[64];
    __shared__ float Red2[64][8];                    // 2 KB

    int tid  = threadIdx.x;
    int lane = tid & 63;
    int wave = tid >> 6;
    int lq   = lane >> 4;   // quad 0..3
    int lc   = lane & 15;   // col in tile

    int blk = blockIdx.x;
    int b   = blk >> 8;
    int n0  = ((blk >> 4) & 15) * 8;
    int m0  = (blk & 15) * 8;

    // stage tn/dn slices (8 rows x 256 f32 each)
    ((float4*)tsl)[tid] = ((const float4*)(tn + (size_t)(b * 128 + n0) * E_DIM))[tid];
    ((float4*)dsl)[tid] = ((const float4*)(dn + (size_t)(b * 128 + m0) * E_DIM))[tid];

    f32x4 acc[4][4];
#pragma unroll
    for (int pt = 0; pt < 4; ++pt)
#pragma unroll
        for (int ht = 0; ht < 4; ++ht)
            acc[pt][ht] = (f32x4){0.f, 0.f, 0.f, 0.f};

    const uint4* Wg = (const uint4*)W1cc;

    for (int c = 0; c < 8; ++c) {
        __syncthreads();  // staging of c-1 reads done / tsl-dsl visible at c=0
        // ---- stage A chunk: Ash[p][kk] = bf16(|t - d|), 64 pairs x 32 k
        {
            int p = tid >> 3, j = tid & 7;
            int nl = p >> 3, ml = p & 7;
            float4 tv = ((const float4*)tsl)[nl * 64 + c * 8 + j];
            float4 dv = ((const float4*)dsl)[ml * 64 + c * 8 + j];
            __bf16* ad = &Ash[p][j * 4];
            ad[0] = (__bf16)fabsf(tv.x - dv.x);
            ad[1] = (__bf16)fabsf(tv.y - dv.y);
            ad[2] = (__bf16)fabsf(tv.z - dv.z);
            ad[3] = (__bf16)fabsf(tv.w - dv.w);
        }
        // ---- stage B chunk: Bsh[h][kk] from chunk-major W1cc (32 KB contiguous)
#pragma unroll
        for (int r = 0; r < 4; ++r) {
            int idx = r * 512 + tid;             // uint4 index in chunk
            uint4 w = Wg[c * 2048 + idx];
            int h = idx >> 2, kb = (idx & 3) * 8;
            uint2* bd = (uint2*)&Bsh[h][kb];
            bd[0] = make_uint2(w.x, w.y);
            bd[1] = make_uint2(w.z, w.w);
        }
        __syncthreads();
        // ---- fragments + MFMA
        bf16x8 af[4], bfr[4];
#pragma unroll
        for (int pt = 0; pt < 4; ++pt)
            af[pt] = __builtin_bit_cast(bf16x8, *(const uint4*)&Ash[pt * 16 + lc][lq * 8]);
#pragma unroll
        for (int ht = 0; ht < 4; ++ht)
            bfr[ht] = __builtin_bit_cast(bf16x8, *(const uint4*)&Bsh[wave * 64 + ht * 16 + lc][lq * 8]);
#pragma unroll
        for (int pt = 0; pt < 4; ++pt)
#pragma unroll
            for (int ht = 0; ht < 4; ++ht)
                acc[pt][ht] = __builtin_amdgcn_mfma_f32_16x16x32_bf16(af[pt], bfr[ht], acc[pt][ht], 0, 0, 0);
    }

    // ---------------- epilogue ----------------
    // C/D layout: col = lc (h within tile), row = lq*4 + reg (pair within tile)
    const float* Pb = P + (size_t)(b * 128 + n0) * H_DIM;
    const float* Qb = Q + (size_t)(b * 128 + m0) * H_DIM;

    // add P (track term + b1) and Q (det term)
#pragma unroll
    for (int pt = 0; pt < 4; ++pt) {
#pragma unroll
        for (int rg = 0; rg < 4; ++rg) {
            int p = pt * 16 + lq * 4 + rg;
            const float* Pr = Pb + (size_t)(p >> 3) * H_DIM;
            const float* Qr = Qb + (size_t)(p & 7) * H_DIM;
#pragma unroll
            for (int ht = 0; ht < 4; ++ht) {
                int h = wave * 64 + ht * 16 + lc;
                acc[pt][ht][rg] += Pr[h] + Qr[h];
            }
        }
    }

    // LayerNorm partial sums (per pair, this wave's 64 h-values)
#pragma unroll
    for (int pt = 0; pt < 4; ++pt) {
#pragma unroll
        for (int rg = 0; rg < 4; ++rg) {
            float s1 = 0.f, s2 = 0.f;
#pragma unroll
            for (int ht = 0; ht < 4; ++ht) {
                float v = acc[pt][ht][rg];
                s1 += v; s2 += v * v;
            }
#pragma unroll
            for (int off = 1; off < 16; off <<= 1) {
                s1 += __shfl_xor(s1, off);
                s2 += __shfl_xor(s2, off);
            }
            if (lc == 0) {
                int p = pt * 16 + lq * 4 + rg;
                LNr1[p][wave] = s1;
                LNr2[p][wave] = s2;
            }
        }
    }
    __syncthreads();
    if (tid < 64) {
        float S1 = 0.f, S2 = 0.f;
#pragma unroll
        for (int w = 0; w < 8; ++w) { S1 += LNr1[tid][w]; S2 += LNr2[tid][w]; }
        float mu = S1 * (1.0f / 512.0f);
        float var = S2 * (1.0f / 512.0f) - mu * mu;
        MuS[tid] = mu;
        RsS[tid] = rsqrtf(var + 1e-5f);
    }
    __syncthreads();

    // normalize + SiLU + W2 dot (per-wave partial over its 64 h)
    float gv[4], bv[4], wv[4];
#pragma unroll
    for (int ht = 0; ht < 4; ++ht) {
        int h = wave * 64 + ht * 16 + lc;
        gv[ht] = gamma[h];
        bv[ht] = beta[h];
        wv[ht] = W2[h];
    }
#pragma unroll
    for (int pt = 0; pt < 4; ++pt) {
#pragma unroll
        for (int rg = 0; rg < 4; ++rg) {
            int p = pt * 16 + lq * 4 + rg;
            float mu = MuS[p], rs = RsS[p];
            float ca = 0.f;
#pragma unroll
            for (int ht = 0; ht < 4; ++ht) {
                float x = (acc[pt][ht][rg] - mu) * rs * gv[ht] + bv[ht];
                float sg = 1.0f / (1.0f + __expf(-x));
                ca += (x * sg) * wv[ht];
            }
#pragma unroll
            for (int off = 1; off < 16; off <<= 1) ca += __shfl_xor(ca, off);
            if (lc == 0) Red2[p][wave] = ca;
        }
    }
    __syncthreads();
    if (tid < 64) {
        float o = b2[0];
#pragma unroll
        for (int w = 0; w < 8; ++w) o += Red2[tid][w];
        int n = n0 + (tid >> 3);
        int m = m0 + (tid & 7);
        out[(size_t)(b * 128 + n) * 128 + m] = o;
    }
}

extern "C" void kernel_launch(void* const* d_in, const int* in_sizes, int n_in,
                              void* d_out, int out_size, void* d_ws, size_t ws_size,
                              hipStream_t stream) {
    const float* track = (const float*)d_in[0];
    const float* det   = (const float*)d_in[1];
    const float* W1    = (const float*)d_in[2];
    const float* b1    = (const float*)d_in[3];
    const float* gamma = (const float*)d_in[4];
    const float* beta  = (const float*)d_in[5];
    const float* W2    = (const float*)d_in[6];
    const float* b2    = (const float*)d_in[7];
    float* out = (float*)d_out;

    char* ws = (char*)d_ws;
    float*  tn    = (float*)(ws);                      // 1 MB  (1024 x 256 f32)
    float*  dn    = (float*)(ws + (1u << 20));         // 1 MB
    float*  P     = (float*)(ws + (2u << 20));         // 2 MB  (1024 x 512 f32)
    float*  Q     = (float*)(ws + (4u << 20));         // 2 MB
    __bf16* W1cc  = (__bf16*)(ws + (6u << 20));        // 256 KB (bf16, chunk-major)

    norm_kernel<<<512, 256, 0, stream>>>(track, det, tn, dn);
    w1c_kernel<<<512, 256, 0, stream>>>(W1, W1cc);
    pq_kernel<<<256, 512, 0, stream>>>(tn, dn, W1, b1, P, Q);
    main_kernel<<<2048, 512, 0, stream>>>(tn, dn, W1cc, P, Q, gamma, beta, W2, b2, out);
}